// Round 5
// baseline (363.861 us; speedup 1.0000x reference)
//
#include <hip/hip_runtime.h>
#include <math.h>

#define B_ 32
#define D_ 16
#define T_ 1024
#define P_ 64
#define L_ 32
#define XSTR 20            // floats per column row: 16 x + x2 + pad (80 B rows)
#define KCH 256            // output columns per chunk (4 chunks)
#define WUP 320            // warm-up columns; w^320 ~ 1e-3 -> truncation error ~0.06 on output
#define NCH (T_ / KCH)

// ---- DPP helpers -----------------------------------------------------------
template<int CTRL, int ROW_MASK, bool BC>
__device__ __forceinline__ float dpp_mov(float old_, float src) {
  int o = __builtin_bit_cast(int, old_);
  int s = __builtin_bit_cast(int, src);
  int r = __builtin_amdgcn_update_dpp(o, s, CTRL, ROW_MASK, 0xf, BC);
  return __builtin_bit_cast(float, r);
}

// Inclusive prefix-sum over each 32-lane half of the wave.
__device__ __forceinline__ float scan_sum32(float v) {
  v += dpp_mov<0x111, 0xf, true>(0.f, v);   // row_shr:1
  v += dpp_mov<0x112, 0xf, true>(0.f, v);   // row_shr:2
  v += dpp_mov<0x114, 0xf, true>(0.f, v);   // row_shr:4
  v += dpp_mov<0x118, 0xf, true>(0.f, v);   // row_shr:8
  v += dpp_mov<0x142, 0xa, false>(0.f, v);  // row_bcast15 -> rows 1,3
  return v;
}

// Inclusive prefix-min over each 32-lane half (old=v; min(v,v)=v identity).
__device__ __forceinline__ float scan_min32(float v) {
  v = fminf(v, dpp_mov<0x111, 0xf, false>(v, v));
  v = fminf(v, dpp_mov<0x112, 0xf, false>(v, v));
  v = fminf(v, dpp_mov<0x114, 0xf, false>(v, v));
  v = fminf(v, dpp_mov<0x118, 0xf, false>(v, v));
  v = fminf(v, dpp_mov<0x142, 0xa, false>(v, v));
  return v;
}

// ---- transpose: x[b][d][t] -> xT[b][t][XSTR] rows (x[0..15], x2 at [16]) ---
__global__ void dtw_transpose(const float* __restrict__ x,
                              float* __restrict__ xT) {
  int gid = blockIdx.x * blockDim.x + threadIdx.x;   // 0 .. B*T-1
  if (gid >= B_ * T_) return;
  int b = gid >> 10;          // / T_
  int j = gid & (T_ - 1);
  float v[D_];
  float s = 0.f;
#pragma unroll
  for (int d = 0; d < D_; ++d) {
    v[d] = x[((size_t)(b * D_ + d)) * T_ + j];       // coalesced over j
    s = fmaf(v[d], v[d], s);
  }
  float* row = xT + (size_t)gid * XSTR;
  float4* dst = (float4*)row;
#pragma unroll
  for (int q = 0; q < 4; ++q)
    dst[q] = make_float4(v[4*q], v[4*q+1], v[4*q+2], v[4*q+3]);
  row[16] = s;
}

// ---- main DTW kernel -------------------------------------------------------
// Grid = B * P/8 * NCH = 1024 blocks of 256 threads -> 4 waves/SIMD: the DP
// chain latency and the (scalar) x-load latency of one wave overlap with the
// other 3 waves' issue. Each block computes output columns [c*KCH,(c+1)*KCH)
// of one (b, 8-pattern) slice, warm-started WUP columns earlier with a
// cumsum-init column (exact for chunks 0,1; error ~ w^WUP ~ 1e-3 for 2,3).
// x column reads are wave-uniform -> s_load (SGPR broadcast, no VALU/LDS).
__global__ __launch_bounds__(256) void dtw_kernel(
    const float* __restrict__ xT,     // [B][T][XSTR]
    const float* __restrict__ patts,  // [P][D][L]
    const float* __restrict__ wp,     // scalar
    float* __restrict__ out)          // [B][P][T]
{
  const int tid = threadIdx.x;
  const int li  = tid & 31;                    // pattern position i
  const int grp = tid >> 5;                    // 0..7
  const int ch  = blockIdx.x & (NCH - 1);      // chunk
  const int bp  = blockIdx.x >> 2;             // 0..255
  const int b   = bp >> 3;
  const int p   = ((bp & 7) << 3) + grp;
  const float w = wp[0];
  const bool lane31 = (li == 31);

  int j0 = ch * KCH - WUP; if (j0 < 0) j0 = 0; // warm-up start (cumsum col)
  const int jstore = ch * KCH;
  const int jend   = ch * KCH + KCH;

  // pattern fragment in registers
  float pd[D_];
  float p2 = 0.f;
#pragma unroll
  for (int d = 0; d < D_; ++d) {
    pd[d] = patts[((size_t)p * D_ + d) * L_ + li];
    p2 = fmaf(pd[d], pd[d], p2);
  }

  const float* xrow = xT + ((size_t)b * T_) * XSTR;
  float* orow = out + ((size_t)(b * P_ + p)) * T_;

  auto costc = [&](const float* xp) -> float {
    float a0 = 0.f, a1 = 0.f, a2 = 0.f, a3 = 0.f;
#pragma unroll
    for (int d = 0; d < D_; d += 4) {
      a0 = fmaf(xp[d + 0], pd[d + 0], a0);
      a1 = fmaf(xp[d + 1], pd[d + 1], a1);
      a2 = fmaf(xp[d + 2], pd[d + 2], a2);
      a3 = fmaf(xp[d + 3], pd[d + 3], a3);
    }
    float dot = (a0 + a1) + (a2 + a3);
    return fmaf(-2.f, dot, xp[16] + p2);
  };

  float dcur;
  // ---- init column at j0: pure cumsum ----
  {
    float c = costc(xrow + (size_t)j0 * XSTR);
    dcur = scan_sum32(c);
    if (ch == 0 && lane31) orow[0] = __builtin_amdgcn_sqrtf(dcur);
  }

  // ---- DP columns j0+1 .. jend-1; store only j >= jstore ----
#pragma unroll 4
  for (int j = j0 + 1; j < jend; ++j) {
    float c = costc(xrow + (size_t)j * XSTR);   // wave-uniform -> s_load

    float S = scan_sum32(c);
    // D[i-1, j-1]: wave_shr:1; lane 0 of each half fixed with dcur (min id.)
    float pu = dpp_mov<0x138, 0xf, false>(dcur, dcur);
    pu = (li == 0) ? dcur : pu;
    float mn = fminf(dcur, pu);
    float e  = fmaf(w, mn, c - S);
    float M  = scan_min32(e);
    dcur = S + M;

    if (lane31 && j >= jstore) orow[j] = __builtin_amdgcn_sqrtf(dcur);
  }
}

extern "C" void kernel_launch(void* const* d_in, const int* in_sizes, int n_in,
                              void* d_out, int out_size, void* d_ws, size_t ws_size,
                              hipStream_t stream) {
  const float* x     = (const float*)d_in[0];
  const float* patts = (const float*)d_in[1];
  const float* w     = (const float*)d_in[2];
  float* out = (float*)d_out;

  float* xT = (float*)d_ws;                  // B*T*XSTR floats = 2.62 MB

  dtw_transpose<<<(B_ * T_ + 255) / 256, 256, 0, stream>>>(x, xT);
  dtw_kernel<<<B_ * (P_ / 8) * NCH, 256, 0, stream>>>(xT, patts, w, out);
}

// Round 6
// 330.568 us; speedup vs baseline: 1.1007x; 1.1007x over previous
//
#include <hip/hip_runtime.h>
#include <math.h>

#define B_ 32
#define D_ 16
#define T_ 1024
#define P_ 64
#define L_ 32
#define XSTR 20            // floats per column row: 16 x + x2 + pad (80 B rows)

// ---- DPP helpers -----------------------------------------------------------
template<int CTRL, int ROW_MASK, bool BC>
__device__ __forceinline__ float dpp_mov(float old_, float src) {
  int o = __builtin_bit_cast(int, old_);
  int s = __builtin_bit_cast(int, src);
  int r = __builtin_amdgcn_update_dpp(o, s, CTRL, ROW_MASK, 0xf, BC);
  return __builtin_bit_cast(float, r);
}

// Inclusive prefix-sum over each 32-lane half of the wave.
__device__ __forceinline__ float scan_sum32(float v) {
  v += dpp_mov<0x111, 0xf, true>(0.f, v);   // row_shr:1
  v += dpp_mov<0x112, 0xf, true>(0.f, v);   // row_shr:2
  v += dpp_mov<0x114, 0xf, true>(0.f, v);   // row_shr:4
  v += dpp_mov<0x118, 0xf, true>(0.f, v);   // row_shr:8
  v += dpp_mov<0x142, 0xa, false>(0.f, v);  // row_bcast15 -> rows 1,3
  return v;
}

// Inclusive prefix-min over each 32-lane half (old=v; min(v,v)=v identity).
__device__ __forceinline__ float scan_min32(float v) {
  v = fminf(v, dpp_mov<0x111, 0xf, false>(v, v));
  v = fminf(v, dpp_mov<0x112, 0xf, false>(v, v));
  v = fminf(v, dpp_mov<0x114, 0xf, false>(v, v));
  v = fminf(v, dpp_mov<0x118, 0xf, false>(v, v));
  v = fminf(v, dpp_mov<0x142, 0xa, false>(v, v));
  return v;
}

// Broadcast lane `lane`'s value of v to all lanes (SGPR result, no memory).
__device__ __forceinline__ float rlane(float v, int lane) {
  return __builtin_bit_cast(float,
      __builtin_amdgcn_readlane(__builtin_bit_cast(int, v), lane));
}

// ---- transpose: x[b][d][t] -> xT[b][t][XSTR] rows (x[0..15], x2 at [16]) ---
__global__ void dtw_transpose(const float* __restrict__ x,
                              float* __restrict__ xT) {
  int gid = blockIdx.x * blockDim.x + threadIdx.x;   // 0 .. B*T-1
  if (gid >= B_ * T_) return;
  int b = gid >> 10;          // / T_
  int j = gid & (T_ - 1);
  float v[D_];
  float s = 0.f;
#pragma unroll
  for (int d = 0; d < D_; ++d) {
    v[d] = x[((size_t)(b * D_ + d)) * T_ + j];       // coalesced over j
    s = fmaf(v[d], v[d], s);
  }
  float* row = xT + (size_t)gid * XSTR;
  float4* dst = (float4*)row;
#pragma unroll
  for (int q = 0; q < 4; ++q)
    dst[q] = make_float4(v[4*q], v[4*q+1], v[4*q+2], v[4*q+3]);
  row[16] = s;
}

// ---- main DTW kernel -------------------------------------------------------
// Block = (b, 8 patterns), 256 threads; 32 lanes = pattern axis L.
// x lives lane-distributed in VGPRs: lane l of each wave holds the 17 floats
// of column (blk*64 + l). Per DP column, 17 v_readlane broadcasts replace all
// memory traffic in the loop — register residency is forced by semantics, so
// the compiler cannot collapse the pipeline back to per-column loads (the
// failure mode of R2-R4: every variant landed at ~620 cyc/col on load stalls).
__global__ __launch_bounds__(256, 1) void dtw_kernel(
    const float* __restrict__ xT,     // [B][T][XSTR]
    const float* __restrict__ patts,  // [P][D][L]
    const float* __restrict__ wp,     // scalar
    float* __restrict__ out)          // [B][P][T]
{
  const int tid = threadIdx.x;
  const int li  = tid & 31;                    // pattern position i
  const int l64 = tid & 63;                    // lane in wave
  const int grp = tid >> 5;                    // 0..7
  const int b   = blockIdx.x >> 3;
  const int p   = ((blockIdx.x & 7) << 3) + grp;
  const float w = wp[0];

  // pattern fragment in registers
  float pd[D_];
  float p2 = 0.f;
#pragma unroll
  for (int d = 0; d < D_; ++d) {
    pd[d] = patts[((size_t)p * D_ + d) * L_ + li];
    p2 = fmaf(pd[d], pd[d], p2);
  }

  const float* xrow = xT + ((size_t)b * T_) * XSTR;
  float* orow = out + ((size_t)(b * P_ + p)) * T_;

  float vx[17], vy[17];   // lane-distributed x blocks (double buffer)

  auto loadblk = [&](int blk, float (&v)[17]) {
    const float* cp = xrow + (size_t)(blk * 64 + l64) * XSTR;
    float4 t0 = *(const float4*)(cp + 0);
    float4 t1 = *(const float4*)(cp + 4);
    float4 t2 = *(const float4*)(cp + 8);
    float4 t3 = *(const float4*)(cp + 12);
    v[0]=t0.x;  v[1]=t0.y;  v[2]=t0.z;  v[3]=t0.w;
    v[4]=t1.x;  v[5]=t1.y;  v[6]=t1.z;  v[7]=t1.w;
    v[8]=t2.x;  v[9]=t2.y;  v[10]=t2.z; v[11]=t2.w;
    v[12]=t3.x; v[13]=t3.y; v[14]=t3.z; v[15]=t3.w;
    v[16]=cp[16];
  };

  float dcur = 0.f;   // j==0 handled via uniform select below

  auto comp64 = [&](int jbase, const float (&v)[17]) {
#pragma unroll 4
    for (int c = 0; c < 64; ++c) {
      const int j = jbase + c;
      float a0 = 0.f, a1 = 0.f, a2 = 0.f, a3 = 0.f;
#pragma unroll
      for (int d = 0; d < D_; d += 4) {
        a0 = fmaf(rlane(v[d + 0], c), pd[d + 0], a0);
        a1 = fmaf(rlane(v[d + 1], c), pd[d + 1], a1);
        a2 = fmaf(rlane(v[d + 2], c), pd[d + 2], a2);
        a3 = fmaf(rlane(v[d + 3], c), pd[d + 3], a3);
      }
      float dot = (a0 + a1) + (a2 + a3);
      float cc = fmaf(-2.f, dot, rlane(v[16], c) + p2);

      float S = scan_sum32(cc);
      // D[i-1, j-1]: wave_shr:1; lane 0 of each half fixed with dcur (min id.)
      float pu = dpp_mov<0x138, 0xf, false>(dcur, dcur);
      pu = (li == 0) ? dcur : pu;
      float mn = fminf(dcur, pu);
      float e  = fmaf(w, mn, cc - S);
      float M  = scan_min32(e);
      dcur = S + ((j == 0) ? 0.f : M);   // j==0 column is pure cumsum
      if (li == 31) orow[j] = sqrtf(dcur);
    }
  };

  loadblk(0, vx);
  for (int bp = 0; bp < 8; ++bp) {
    loadblk(2 * bp + 1, vy);             // prefetch odd block
    comp64(128 * bp, vx);
    int nb = 2 * bp + 2; if (nb > 15) nb = 15;
    loadblk(nb, vx);                     // prefetch even block (clamped)
    comp64(128 * bp + 64, vy);
  }
}

extern "C" void kernel_launch(void* const* d_in, const int* in_sizes, int n_in,
                              void* d_out, int out_size, void* d_ws, size_t ws_size,
                              hipStream_t stream) {
  const float* x     = (const float*)d_in[0];
  const float* patts = (const float*)d_in[1];
  const float* w     = (const float*)d_in[2];
  float* out = (float*)d_out;

  float* xT = (float*)d_ws;                  // B*T*XSTR floats = 2.62 MB

  dtw_transpose<<<(B_ * T_ + 255) / 256, 256, 0, stream>>>(x, xT);
  dtw_kernel<<<B_ * (P_ / 8), 256, 0, stream>>>(xT, patts, w, out);
}